// Round 2
// baseline (142.924 us; speedup 1.0000x reference)
//
#include <hip/hip_runtime.h>

#define HH 256
#define WW 512
#define CC 64
#define CO 16
#define DD 48   // MAX_DISPARITY; output has D+1 = 49 disparity planes

typedef float f32x4 __attribute__((ext_vector_type(4)));

// Kernel 1: per-pixel 16x64 matvec for both L and R projections.
// One thread per (y,x) pixel. W reads are wave-uniform -> scalar loads.
__global__ __launch_bounds__(256) void lr_project(
    const float* __restrict__ left, const float* __restrict__ right,
    const float* __restrict__ Wop,
    float* __restrict__ Lout, float* __restrict__ Rout)
{
    const int tid = blockIdx.x * blockDim.x + threadIdx.x;  // 0 .. H*W-1
    const int x = tid & (WW - 1);
    const int y = tid >> 9;   // /512

    float accL[CO], accR[CO];
#pragma unroll
    for (int o = 0; o < CO; ++o) { accL[o] = 0.0f; accR[o] = 0.0f; }

#pragma unroll 4
    for (int c = 0; c < CC; ++c) {
        const float l = left [(c * HH + y) * WW + x];
        const float r = right[(c * HH + y) * WW + x];
#pragma unroll
        for (int o = 0; o < CO; ++o) {
            accL[o] += Wop[o * (2 * CC) + c]      * l;
            accR[o] += Wop[o * (2 * CC) + CC + c] * r;
        }
    }

#pragma unroll
    for (int o = 0; o < CO; ++o) {
        Lout[(o * HH + y) * WW + x] = accL[o];
        Rout[(o * HH + y) * WW + x] = accR[o];
    }
}

// Kernel 2: out[o,d,y,x] = L[o,y,x] + (x>=d ? R[o,y,x-d] : 0) + b[o]
// Grid-stride over float4 groups; linear index matches output layout.
__global__ __launch_bounds__(256) void assemble(
    const float* __restrict__ L, const float* __restrict__ R,
    const float* __restrict__ bop, float* __restrict__ out)
{
    const int total4 = CO * (DD + 1) * HH * (WW / 4);   // 25,690,112
    const int stride = gridDim.x * blockDim.x;

    for (int i = blockIdx.x * blockDim.x + threadIdx.x; i < total4; i += stride) {
        const int x4 = i & 127;          // W/4 = 128
        const int t  = i >> 7;
        const int y  = t & 255;          // H = 256
        const int t2 = t >> 8;
        const int d  = t2 % (DD + 1);
        const int o  = t2 / (DD + 1);

        const int x = x4 * 4;
        const f32x4 lv = *reinterpret_cast<const f32x4*>(&L[(o * HH + y) * WW + x]);
        const float b  = bop[o];
        const float* Rrow = &R[(o * HH + y) * WW];

        // predicated loads: address may be OOB (below buffer) when x-d < 0
        const float r0 = (x + 0 >= d) ? Rrow[x + 0 - d] : 0.0f;
        const float r1 = (x + 1 >= d) ? Rrow[x + 1 - d] : 0.0f;
        const float r2 = (x + 2 >= d) ? Rrow[x + 2 - d] : 0.0f;
        const float r3 = (x + 3 >= d) ? Rrow[x + 3 - d] : 0.0f;

        f32x4 ov;
        ov.x = lv.x + r0 + b;
        ov.y = lv.y + r1 + b;
        ov.z = lv.z + r2 + b;
        ov.w = lv.w + r3 + b;

        __builtin_nontemporal_store(ov, reinterpret_cast<f32x4*>(&out[(size_t)i * 4]));
    }
}

extern "C" void kernel_launch(void* const* d_in, const int* in_sizes, int n_in,
                              void* d_out, int out_size, void* d_ws, size_t ws_size,
                              hipStream_t stream) {
    const float* left  = (const float*)d_in[0];
    const float* right = (const float*)d_in[1];
    const float* Wop   = (const float*)d_in[2];
    const float* bop   = (const float*)d_in[3];
    float* out = (float*)d_out;

    float* Lws = (float*)d_ws;                      // CO*H*W floats = 8 MB
    float* Rws = Lws + (size_t)CO * HH * WW;        // next 8 MB

    // Kernel 1: 131072 pixels, 256 threads/block -> 512 blocks
    lr_project<<<(HH * WW) / 256, 256, 0, stream>>>(left, right, Wop, Lws, Rws);

    // Kernel 2: 2048 blocks x 256 threads, grid-stride (exactly 49 iters/thread)
    assemble<<<2048, 256, 0, stream>>>(Lws, Rws, bop, out);
}

// Round 3
// 105.853 us; speedup vs baseline: 1.3502x; 1.3502x over previous
//
#include <hip/hip_runtime.h>

#define HH 256
#define WW 512
#define CC 64
#define CO 16
#define DD 48   // MAX_DISPARITY; output has D+1 = 49 disparity planes

typedef float f32x4 __attribute__((ext_vector_type(4)));

// Kernel 1: per-pixel 16x64 matvec for both L and R projections.
// One thread per (y,x) pixel. W reads are wave-uniform -> scalar loads.
__global__ __launch_bounds__(256) void lr_project(
    const float* __restrict__ left, const float* __restrict__ right,
    const float* __restrict__ Wop,
    float* __restrict__ Lout, float* __restrict__ Rout)
{
    const int tid = blockIdx.x * blockDim.x + threadIdx.x;  // 0 .. H*W-1
    const int x = tid & (WW - 1);
    const int y = tid >> 9;   // /512

    float accL[CO], accR[CO];
#pragma unroll
    for (int o = 0; o < CO; ++o) { accL[o] = 0.0f; accR[o] = 0.0f; }

#pragma unroll 4
    for (int c = 0; c < CC; ++c) {
        const float l = left [(c * HH + y) * WW + x];
        const float r = right[(c * HH + y) * WW + x];
#pragma unroll
        for (int o = 0; o < CO; ++o) {
            accL[o] += Wop[o * (2 * CC) + c]      * l;
            accR[o] += Wop[o * (2 * CC) + CC + c] * r;
        }
    }

#pragma unroll
    for (int o = 0; o < CO; ++o) {
        Lout[(o * HH + y) * WW + x] = accL[o];
        Rout[(o * HH + y) * WW + x] = accR[o];
    }
}

// Kernel 2: out[o,d,y,x] = L[o,y,x] + (x>=d ? R[o,y,x-d] : 0) + b[o]
// One thread per (o,y,x4); loop over d with a sliding R window:
//   r_k(d+1) = r_{k-1}(d), one new predicated scalar load per d.
// Per d: 1 dword load + 1 NT dwordx4 store + 4 adds. Store pointer walks
// plane stride H*W — coalesced across lanes (consecutive x4).
__global__ __launch_bounds__(256) void assemble(
    const float* __restrict__ L, const float* __restrict__ R,
    const float* __restrict__ bop, float* __restrict__ out)
{
    const int tid = blockIdx.x * blockDim.x + threadIdx.x;  // 0 .. CO*H*W/4-1
    const int x4 = tid & 127;        // W/4 = 128
    const int t  = tid >> 7;
    const int y  = t & 255;          // H = 256
    const int o  = t >> 8;

    const int x   = x4 * 4;
    const int row = (o * HH + y) * WW;

    const float  b  = bop[o];
    const f32x4  lv = *reinterpret_cast<const f32x4*>(&L[row + x]);
    const float lb0 = lv.x + b, lb1 = lv.y + b, lb2 = lv.z + b, lb3 = lv.w + b;

    const float* Rrow = &R[row];
    float r0 = Rrow[x + 0];
    float r1 = Rrow[x + 1];
    float r2 = Rrow[x + 2];
    float r3 = Rrow[x + 3];

    float* outp = &out[((size_t)(o * (DD + 1)) * HH + y) * WW + x];

#pragma unroll
    for (int d = 0; d <= DD; ++d) {
        f32x4 ov;
        ov.x = lb0 + r0;
        ov.y = lb1 + r1;
        ov.z = lb2 + r2;
        ov.w = lb3 + r3;
        __builtin_nontemporal_store(ov, reinterpret_cast<f32x4*>(outp));
        outp += HH * WW;             // next disparity plane

        // slide window left by one (predicated: address may be OOB below R)
        r3 = r2; r2 = r1; r1 = r0;
        const int nx = x - d - 1;
        r0 = (nx >= 0) ? Rrow[nx] : 0.0f;
    }
}

extern "C" void kernel_launch(void* const* d_in, const int* in_sizes, int n_in,
                              void* d_out, int out_size, void* d_ws, size_t ws_size,
                              hipStream_t stream) {
    const float* left  = (const float*)d_in[0];
    const float* right = (const float*)d_in[1];
    const float* Wop   = (const float*)d_in[2];
    const float* bop   = (const float*)d_in[3];
    float* out = (float*)d_out;

    float* Lws = (float*)d_ws;                      // CO*H*W floats = 8 MB
    float* Rws = Lws + (size_t)CO * HH * WW;        // next 8 MB

    // Kernel 1: 131072 pixels, 256 threads/block -> 512 blocks
    lr_project<<<(HH * WW) / 256, 256, 0, stream>>>(left, right, Wop, Lws, Rws);

    // Kernel 2: one thread per (o,y,x4): 16*256*128 = 524288 threads -> 2048 blocks
    assemble<<<(CO * HH * (WW / 4)) / 256, 256, 0, stream>>>(Lws, Rws, bop, out);
}

// Round 4
// 104.677 us; speedup vs baseline: 1.3654x; 1.0112x over previous
//
#include <hip/hip_runtime.h>

#define HH 256
#define WW 512
#define CC 64
#define CO 16
#define DD 48   // MAX_DISPARITY; output has D+1 = 49 disparity planes

typedef float f32x4 __attribute__((ext_vector_type(4)));

// Kernel 1: per-pixel 16x64 matvec for both L and R projections.
__global__ __launch_bounds__(256) void lr_project(
    const float* __restrict__ left, const float* __restrict__ right,
    const float* __restrict__ Wop,
    float* __restrict__ Lout, float* __restrict__ Rout)
{
    const int tid = blockIdx.x * blockDim.x + threadIdx.x;  // 0 .. H*W-1
    const int x = tid & (WW - 1);
    const int y = tid >> 9;   // /512

    float accL[CO], accR[CO];
#pragma unroll
    for (int o = 0; o < CO; ++o) { accL[o] = 0.0f; accR[o] = 0.0f; }

#pragma unroll 4
    for (int c = 0; c < CC; ++c) {
        const float l = left [(c * HH + y) * WW + x];
        const float r = right[(c * HH + y) * WW + x];
#pragma unroll
        for (int o = 0; o < CO; ++o) {
            accL[o] += Wop[o * (2 * CC) + c]      * l;
            accR[o] += Wop[o * (2 * CC) + CC + c] * r;
        }
    }

#pragma unroll
    for (int o = 0; o < CO; ++o) {
        Lout[(o * HH + y) * WW + x] = accL[o];
        Rout[(o * HH + y) * WW + x] = accR[o];
    }
}

// Kernel 2: out[o,d,y,x] = L[o,y,x] + (x>=d ? R[o,y,x-d] : 0) + b[o]
// One thread per (o,y,x4). Preload the entire R window R[x-48 .. x+3]
// (13 aligned float4 -> 52 registers, each vector fully valid or fully OOB),
// then 49 iterations of pure {4 adds + 1 NT dwordx4 store} — no in-loop loads,
// no serial dependence. Store pointer walks the disparity-plane stride.
__global__ __launch_bounds__(256) void assemble(
    const float* __restrict__ L, const float* __restrict__ R,
    const float* __restrict__ bop, float* __restrict__ out)
{
    const int tid = blockIdx.x * blockDim.x + threadIdx.x;  // 0 .. CO*H*W/4-1
    const int x4 = tid & 127;        // W/4 = 128
    const int t  = tid >> 7;
    const int y  = t & 255;          // H = 256
    const int o  = t >> 8;

    const int x   = x4 * 4;
    const int row = (o * HH + y) * WW;

    const float  b  = bop[o];
    const f32x4  lv = *reinterpret_cast<const f32x4*>(&L[row + x]);
    const float lb0 = lv.x + b, lb1 = lv.y + b, lb2 = lv.z + b, lb3 = lv.w + b;

    const float* Rrow = &R[row];

    // w[k] = R[row + x - 48 + k] for k=0..51 (zero where x-48+k < 0).
    // Loaded in REVERSE j order so d=0's operands (j=12) arrive first.
    float w[52];
#pragma unroll
    for (int jr = 0; jr < 13; ++jr) {
        const int j = 12 - jr;
        const int base = x - 48 + 4 * j;
        // speculative aligned load; base >= -48 stays inside d_ws (L region)
        f32x4 v = *reinterpret_cast<const f32x4*>(&Rrow[base]);
        const bool ok = (base >= 0);
        w[4 * j + 0] = ok ? v.x : 0.0f;
        w[4 * j + 1] = ok ? v.y : 0.0f;
        w[4 * j + 2] = ok ? v.z : 0.0f;
        w[4 * j + 3] = ok ? v.w : 0.0f;
    }

    float* outp = &out[((size_t)(o * (DD + 1)) * HH + y) * WW + x];

#pragma unroll
    for (int d = 0; d <= DD; ++d) {
        f32x4 ov;
        ov.x = lb0 + w[48 - d];
        ov.y = lb1 + w[49 - d];
        ov.z = lb2 + w[50 - d];
        ov.w = lb3 + w[51 - d];
        __builtin_nontemporal_store(ov, reinterpret_cast<f32x4*>(outp));
        outp += HH * WW;             // next disparity plane
    }
}

extern "C" void kernel_launch(void* const* d_in, const int* in_sizes, int n_in,
                              void* d_out, int out_size, void* d_ws, size_t ws_size,
                              hipStream_t stream) {
    const float* left  = (const float*)d_in[0];
    const float* right = (const float*)d_in[1];
    const float* Wop   = (const float*)d_in[2];
    const float* bop   = (const float*)d_in[3];
    float* out = (float*)d_out;

    float* Lws = (float*)d_ws;                      // CO*H*W floats = 8 MB
    float* Rws = Lws + (size_t)CO * HH * WW;        // next 8 MB

    lr_project<<<(HH * WW) / 256, 256, 0, stream>>>(left, right, Wop, Lws, Rws);
    assemble<<<(CO * HH * (WW / 4)) / 256, 256, 0, stream>>>(Lws, Rws, bop, out);
}